// Round 1
// baseline (210.779 us; speedup 1.0000x reference)
//
#include <hip/hip_runtime.h>
#include <hip/hip_bf16.h>

// DCNv2 forward: B=2, C=256, H=W=96, O=256, K=3x3, stride=1, pad=1, dil=1.
// Pipeline:
//  K1 transpose_pack : input  NCHW fp32 -> NHWC bf16   (d_ws, 9.4 MB)
//  K2 weight_pack    : weight [O][C][k] fp32 -> bf16 [O][k*256+c] (d_ws+9.4MB, 1.2MB)
//  K3 dcn_main       : fused bilinear-sample (+mask) -> LDS col tile -> MFMA GEMM
//
// Per block (256 thr = 4 waves): batch b, 64 spatial positions, ALL 256 output
// channels (col tile built once, reused by 4 waves x 64 O each).
// MFMA 16x16x32 bf16: A=weight (M=O), B=col (N=s); D row=quad*4+reg (o),
// col=lane&15 (s)  [m89 mapping].

#define Hh 96
#define Ww 96
#define Cc 256
#define Oo 256
#define Bb 2
#define Kk 9
#define Ss (Hh * Ww)          // 9216
#define STILE 64
#define CKTOT (Cc * Kk)       // 2304

typedef __bf16 bf16x8 __attribute__((ext_vector_type(8)));
typedef __bf16 bf16x4v __attribute__((ext_vector_type(4)));
typedef __bf16 bf16x2v __attribute__((ext_vector_type(2)));
typedef float f32x4 __attribute__((ext_vector_type(4)));

__device__ __forceinline__ float blo(unsigned u) { return __uint_as_float(u << 16); }
__device__ __forceinline__ float bhi(unsigned u) { return __uint_as_float(u & 0xffff0000u); }

// ---------------- K1: NCHW fp32 -> NHWC bf16 ----------------
__global__ __launch_bounds__(256) void transpose_pack(const float* __restrict__ inp,
                                                      __bf16* __restrict__ it) {
  __shared__ float tile[64][65];  // +1 pad breaks bank conflicts
  const int hw0 = blockIdx.x * 64;
  const int c0 = blockIdx.y * 64;
  const int b = blockIdx.z;
  const int tid = threadIdx.x;

  // load: lanes -> hw (coalesced 256B per c-row)
  const int hw_l = tid & 63, cr = tid >> 6;
  const float* src = inp + ((size_t)(b * Cc + c0) * Ss) + hw0;
#pragma unroll
  for (int r = 0; r < 16; ++r) {
    int c_l = r * 4 + cr;
    tile[c_l][hw_l] = src[(size_t)c_l * Ss + hw_l];
  }
  __syncthreads();

  // store: lanes -> c pairs (coalesced 128B per hw-row)
  const int cp = (tid & 31) * 2, hr = tid >> 5;
  __bf16* dst = it + ((size_t)(b * Ss + hw0) * Cc) + c0;
#pragma unroll
  for (int r = 0; r < 8; ++r) {
    int hw_s = r * 8 + hr;
    bf16x2v p;
    p.x = (__bf16)tile[cp][hw_s];
    p.y = (__bf16)tile[cp + 1][hw_s];
    *(bf16x2v*)(dst + (size_t)hw_s * Cc + cp) = p;
  }
}

// ---------------- K2: weight [O][C][k] -> bf16 [O][k*256+c] ----------------
__global__ __launch_bounds__(256) void weight_pack(const float* __restrict__ wsrc,
                                                   __bf16* __restrict__ wt) {
  int i = blockIdx.x * 256 + threadIdx.x;  // i < Oo*CKTOT
  int o = i / CKTOT;
  int r = i - o * CKTOT;
  int k = r >> 8, c = r & 255;
  wt[i] = (__bf16)wsrc[(o * Cc + c) * Kk + k];
}

// ---------------- K3: fused sample + GEMM ----------------
__global__ __launch_bounds__(256, 2) void dcn_main(
    const __bf16* __restrict__ it,     // [B][S][C] bf16
    const __bf16* __restrict__ wt,     // [O][k*256+c] bf16
    const float* __restrict__ offset,  // [B][18][S]
    const float* __restrict__ mask,    // [B][9][S]
    const float* __restrict__ bias,    // [O]
    float* __restrict__ out)           // [B][O][S]
{
  __shared__ __bf16 colT[64][48];  // [s][c-in-chunk], rows padded 32->48 (96B, 16B-aligned)
  __shared__ int4 pa[64];          // 4 corner row offsets (elements) per s
  __shared__ float4 pw[64];        // 4 corner weights (mask+validity folded) per s

  const int tid = threadIdx.x;
  const int s0 = blockIdx.x * STILE;
  const int b = blockIdx.y;
  const int lane = tid & 63;
  const int wv = tid >> 6;        // wave id 0..3 -> O sub-block of 64
  const int quad = lane >> 4;     // 0..3
  const int l15 = lane & 15;

  const __bf16* itb = it + (size_t)b * Ss * Cc;

  f32x4 acc[4][4];
#pragma unroll
  for (int i = 0; i < 4; ++i)
#pragma unroll
    for (int j = 0; j < 4; ++j) acc[i][j] = (f32x4){0.f, 0.f, 0.f, 0.f};

  // fill-phase thread coords: 8 c-groups (4ch each) x 32 s per pass
  const int cg = tid & 7;
  const int sg = tid >> 3;

  for (int k = 0; k < Kk; ++k) {
    // per-(k,s) bilinear params, computed once, reused over 8 c-chunks
    if (tid < 64) {
      int s = s0 + tid;
      int ho = s / Ww;
      int wo = s - ho * Ww;
      float dy = offset[((size_t)(b * 18 + 2 * k)) * Ss + s];
      float dx = offset[((size_t)(b * 18 + 2 * k + 1)) * Ss + s];
      float m = mask[((size_t)(b * 9 + k)) * Ss + s];
      float y = (float)(ho - 1 + k / 3) + dy;
      float x = (float)(wo - 1 + k % 3) + dx;
      float fy = floorf(y), fx = floorf(x);
      int y0 = (int)fy, x0 = (int)fx;
      float wy = y - fy, wx = x - fx;
      int y1 = y0 + 1, x1 = x0 + 1;
      float vy0 = (y0 >= 0 && y0 < Hh) ? 1.f : 0.f;
      float vy1 = (y1 >= 0 && y1 < Hh) ? 1.f : 0.f;
      float vx0 = (x0 >= 0 && x0 < Ww) ? 1.f : 0.f;
      float vx1 = (x1 >= 0 && x1 < Ww) ? 1.f : 0.f;
      int y0c = min(max(y0, 0), Hh - 1), y1c = min(max(y1, 0), Hh - 1);
      int x0c = min(max(x0, 0), Ww - 1), x1c = min(max(x1, 0), Ww - 1);
      pa[tid] = make_int4((y0c * Ww + x0c) * Cc, (y0c * Ww + x1c) * Cc,
                          (y1c * Ww + x0c) * Cc, (y1c * Ww + x1c) * Cc);
      pw[tid] = make_float4(m * (1.f - wy) * (1.f - wx) * vy0 * vx0,
                            m * (1.f - wy) * wx * vy0 * vx1,
                            m * wy * (1.f - wx) * vy1 * vx0,
                            m * wy * wx * vy1 * vx1);
    }
    const int kbase = k * 256;

    for (int cc = 0; cc < Cc; cc += 32) {
      __syncthreads();  // prev MFMA done with colT; params visible (cc==0)

      // ---- fill colT[64][0..31] for this (k, c-chunk) ----
#pragma unroll
      for (int p = 0; p < 2; ++p) {
        int sl = p * 32 + sg;
        int4 a = pa[sl];
        float4 wq = pw[sl];
        const __bf16* bp = itb + (cc + (cg << 2));
        uint2 u00 = *(const uint2*)(bp + a.x);
        uint2 u01 = *(const uint2*)(bp + a.y);
        uint2 u10 = *(const uint2*)(bp + a.z);
        uint2 u11 = *(const uint2*)(bp + a.w);
        float r0 = wq.x * blo(u00.x) + wq.y * blo(u01.x) + wq.z * blo(u10.x) + wq.w * blo(u11.x);
        float r1 = wq.x * bhi(u00.x) + wq.y * bhi(u01.x) + wq.z * bhi(u10.x) + wq.w * bhi(u11.x);
        float r2 = wq.x * blo(u00.y) + wq.y * blo(u01.y) + wq.z * blo(u10.y) + wq.w * blo(u11.y);
        float r3 = wq.x * bhi(u00.y) + wq.y * bhi(u01.y) + wq.z * bhi(u10.y) + wq.w * bhi(u11.y);
        bf16x4v rv;
        rv.x = (__bf16)r0;
        rv.y = (__bf16)r1;
        rv.z = (__bf16)r2;
        rv.w = (__bf16)r3;
        *(bf16x4v*)&colT[sl][cg << 2] = rv;
      }
      __syncthreads();

      // ---- MFMA: 4 O-subtiles x 4 S-subtiles per wave ----
      bf16x8 af[4];
      const __bf16* wbase = wt + (size_t)(kbase + cc) + quad * 8;
#pragma unroll
      for (int ot = 0; ot < 4; ++ot) {
        int o = wv * 64 + ot * 16 + l15;
        af[ot] = *(const bf16x8*)(wbase + (size_t)o * CKTOT);
      }
      bf16x8 bfr[4];
#pragma unroll
      for (int st = 0; st < 4; ++st)
        bfr[st] = *(const bf16x8*)(&colT[st * 16 + l15][quad * 8]);
#pragma unroll
      for (int ot = 0; ot < 4; ++ot)
#pragma unroll
        for (int st = 0; st < 4; ++st)
          acc[ot][st] =
              __builtin_amdgcn_mfma_f32_16x16x32_bf16(af[ot], bfr[st], acc[ot][st], 0, 0, 0);
    }
  }

  // ---- epilogue: bias + store fp32 ----
  float* ob = out + (size_t)(b * Oo) * Ss + s0;
#pragma unroll
  for (int ot = 0; ot < 4; ++ot) {
    int obase = wv * 64 + ot * 16 + quad * 4;
#pragma unroll
    for (int r = 0; r < 4; ++r) {
      float bi = bias[obase + r];
#pragma unroll
      for (int st = 0; st < 4; ++st) {
        ob[(size_t)(obase + r) * Ss + st * 16 + l15] = acc[ot][st][r] + bi;
      }
    }
  }
}

extern "C" void kernel_launch(void* const* d_in, const int* in_sizes, int n_in,
                              void* d_out, int out_size, void* d_ws, size_t ws_size,
                              hipStream_t stream) {
  (void)in_sizes; (void)n_in; (void)out_size; (void)ws_size;
  const float* inp = (const float*)d_in[0];
  const float* offset = (const float*)d_in[1];
  const float* mask = (const float*)d_in[2];
  const float* weight = (const float*)d_in[3];
  const float* bias = (const float*)d_in[4];
  float* out = (float*)d_out;

  __bf16* it = (__bf16*)d_ws;                                         // 9,437,184 B
  __bf16* wt = (__bf16*)((char*)d_ws + (size_t)Bb * Ss * Cc * 2);     // 1,179,648 B

  transpose_pack<<<dim3(Ss / 64, Cc / 64, Bb), 256, 0, stream>>>(inp, it);
  weight_pack<<<(Oo * CKTOT) / 256, 256, 0, stream>>>(weight, wt);
  dcn_main<<<dim3(Ss / STILE, Bb), 256, 0, stream>>>(it, wt, offset, mask, bias, out);
}

// Round 2
// 187.612 us; speedup vs baseline: 1.1235x; 1.1235x over previous
//
#include <hip/hip_runtime.h>
#include <hip/hip_bf16.h>

// DCNv2 forward: B=2, C=256, H=W=96, O=256, K=3x3, stride=1, pad=1, dil=1.
// Pipeline:
//  K1 transpose_pack : input  NCHW fp32 -> NHWC bf16   (d_ws, 9.4 MB)
//  K2 weight_pack    : weight [O][C][k] fp32 -> bf16 [O][k*256+c] (d_ws+9.4MB, 1.2MB)
//  K3 bias_init      : out[b][o][s] = bias[o]  (out re-poisoned each call)
//  K4 dcn_main       : fused bilinear-sample -> LDS col tile -> MFMA, atomicAdd
//
// R1: grid was 288 blocks -> 2-round makespan, 11% occupancy, all pipes idle.
// Now: k-split=3 (taps {0-2},{3-5},{6-8}), 512-thr blocks (8 waves x 32 O),
// grid = 144 x 2 x 3 = 864 blocks (~27 waves/CU). Partials atomicAdd'ed.

#define Hh 96
#define Ww 96
#define Cc 256
#define Oo 256
#define Bb 2
#define Kk 9
#define Ss (Hh * Ww)          // 9216
#define STILE 64
#define CKTOT (Cc * Kk)       // 2304

typedef __bf16 bf16x8 __attribute__((ext_vector_type(8)));
typedef __bf16 bf16x4v __attribute__((ext_vector_type(4)));
typedef __bf16 bf16x2v __attribute__((ext_vector_type(2)));
typedef float f32x4 __attribute__((ext_vector_type(4)));

__device__ __forceinline__ float blo(unsigned u) { return __uint_as_float(u << 16); }
__device__ __forceinline__ float bhi(unsigned u) { return __uint_as_float(u & 0xffff0000u); }

// ---------------- K1: NCHW fp32 -> NHWC bf16 ----------------
__global__ __launch_bounds__(256) void transpose_pack(const float* __restrict__ inp,
                                                      __bf16* __restrict__ it) {
  __shared__ float tile[64][65];  // +1 pad breaks bank conflicts
  const int hw0 = blockIdx.x * 64;
  const int c0 = blockIdx.y * 64;
  const int b = blockIdx.z;
  const int tid = threadIdx.x;

  const int hw_l = tid & 63, cr = tid >> 6;
  const float* src = inp + ((size_t)(b * Cc + c0) * Ss) + hw0;
#pragma unroll
  for (int r = 0; r < 16; ++r) {
    int c_l = r * 4 + cr;
    tile[c_l][hw_l] = src[(size_t)c_l * Ss + hw_l];
  }
  __syncthreads();

  const int cp = (tid & 31) * 2, hr = tid >> 5;
  __bf16* dst = it + ((size_t)(b * Ss + hw0) * Cc) + c0;
#pragma unroll
  for (int r = 0; r < 8; ++r) {
    int hw_s = r * 8 + hr;
    bf16x2v p;
    p.x = (__bf16)tile[cp][hw_s];
    p.y = (__bf16)tile[cp + 1][hw_s];
    *(bf16x2v*)(dst + (size_t)hw_s * Cc + cp) = p;
  }
}

// ---------------- K2: weight [O][C][k] -> bf16 [O][k*256+c] ----------------
__global__ __launch_bounds__(256) void weight_pack(const float* __restrict__ wsrc,
                                                   __bf16* __restrict__ wt) {
  int i = blockIdx.x * 256 + threadIdx.x;  // i < Oo*CKTOT
  int o = i / CKTOT;
  int r = i - o * CKTOT;
  int k = r >> 8, c = r & 255;
  wt[i] = (__bf16)wsrc[(o * Cc + c) * Kk + k];
}

// ---------------- K3: out = bias (broadcast) ----------------
__global__ __launch_bounds__(256) void bias_init(const float* __restrict__ bias,
                                                 float* __restrict__ out) {
  int i = blockIdx.x * 256 + threadIdx.x;  // indexes float4; total Bb*Oo*Ss/4
  const int s4 = Ss / 4;
  int o = (i / s4) & (Oo - 1);
  float bv = bias[o];
  ((float4*)out)[i] = make_float4(bv, bv, bv, bv);
}

// ---------------- K4: fused sample + GEMM (k-split, atomic accumulate) ----
__global__ __launch_bounds__(512, 4) void dcn_main(
    const __bf16* __restrict__ it,     // [B][S][C] bf16
    const __bf16* __restrict__ wt,     // [O][k*256+c] bf16
    const float* __restrict__ offset,  // [B][18][S]
    const float* __restrict__ mask,    // [B][9][S]
    float* __restrict__ out)           // [B][O][S], pre-filled with bias
{
  __shared__ __bf16 colT[64][48];  // [s][c-in-chunk], rows padded 32->48
  __shared__ int4 pa[64];          // 4 corner row offsets (elements) per s
  __shared__ float4 pw[64];        // 4 corner weights (mask+validity folded)

  const int tid = threadIdx.x;
  const int s0 = blockIdx.x * STILE;
  const int b = blockIdx.y;
  const int kg = blockIdx.z;      // tap group: taps kg*3 .. kg*3+2
  const int lane = tid & 63;
  const int wv = tid >> 6;        // wave id 0..7 -> O sub-block of 32
  const int quad = lane >> 4;     // 0..3
  const int l15 = lane & 15;

  const __bf16* itb = it + (size_t)b * Ss * Cc;

  f32x4 acc[2][4];
#pragma unroll
  for (int i = 0; i < 2; ++i)
#pragma unroll
    for (int j = 0; j < 4; ++j) acc[i][j] = (f32x4){0.f, 0.f, 0.f, 0.f};

  // fill-phase coords: 8 c-groups (4ch each) x 64 s, one elem quad per thread
  const int cg = tid & 7;
  const int sg = tid >> 3;

  for (int j = 0; j < 3; ++j) {
    const int k = kg * 3 + j;
    if (tid < 64) {
      int s = s0 + tid;
      int ho = s / Ww;
      int wo = s - ho * Ww;
      float dy = offset[((size_t)(b * 18 + 2 * k)) * Ss + s];
      float dx = offset[((size_t)(b * 18 + 2 * k + 1)) * Ss + s];
      float m = mask[((size_t)(b * 9 + k)) * Ss + s];
      float y = (float)(ho - 1 + k / 3) + dy;
      float x = (float)(wo - 1 + k % 3) + dx;
      float fy = floorf(y), fx = floorf(x);
      int y0 = (int)fy, x0 = (int)fx;
      float wy = y - fy, wx = x - fx;
      int y1 = y0 + 1, x1 = x0 + 1;
      float vy0 = (y0 >= 0 && y0 < Hh) ? 1.f : 0.f;
      float vy1 = (y1 >= 0 && y1 < Hh) ? 1.f : 0.f;
      float vx0 = (x0 >= 0 && x0 < Ww) ? 1.f : 0.f;
      float vx1 = (x1 >= 0 && x1 < Ww) ? 1.f : 0.f;
      int y0c = min(max(y0, 0), Hh - 1), y1c = min(max(y1, 0), Hh - 1);
      int x0c = min(max(x0, 0), Ww - 1), x1c = min(max(x1, 0), Ww - 1);
      pa[tid] = make_int4((y0c * Ww + x0c) * Cc, (y0c * Ww + x1c) * Cc,
                          (y1c * Ww + x0c) * Cc, (y1c * Ww + x1c) * Cc);
      pw[tid] = make_float4(m * (1.f - wy) * (1.f - wx) * vy0 * vx0,
                            m * (1.f - wy) * wx * vy0 * vx1,
                            m * wy * (1.f - wx) * vy1 * vx0,
                            m * wy * wx * vy1 * vx1);
    }
    const int kbase = k * 256;

    for (int cc = 0; cc < Cc; cc += 32) {
      __syncthreads();  // prev MFMA done with colT; params visible (cc==0)

      // ---- fill colT[64][0..31] for this (k, c-chunk) ----
      {
        int4 a = pa[sg];
        float4 wq = pw[sg];
        const __bf16* bp = itb + (cc + (cg << 2));
        uint2 u00 = *(const uint2*)(bp + a.x);
        uint2 u01 = *(const uint2*)(bp + a.y);
        uint2 u10 = *(const uint2*)(bp + a.z);
        uint2 u11 = *(const uint2*)(bp + a.w);
        float r0 = wq.x * blo(u00.x) + wq.y * blo(u01.x) + wq.z * blo(u10.x) + wq.w * blo(u11.x);
        float r1 = wq.x * bhi(u00.x) + wq.y * bhi(u01.x) + wq.z * bhi(u10.x) + wq.w * bhi(u11.x);
        float r2 = wq.x * blo(u00.y) + wq.y * blo(u01.y) + wq.z * blo(u10.y) + wq.w * blo(u11.y);
        float r3 = wq.x * bhi(u00.y) + wq.y * bhi(u01.y) + wq.z * bhi(u10.y) + wq.w * bhi(u11.y);
        bf16x4v rv;
        rv.x = (__bf16)r0;
        rv.y = (__bf16)r1;
        rv.z = (__bf16)r2;
        rv.w = (__bf16)r3;
        *(bf16x4v*)&colT[sg][cg << 2] = rv;
      }
      __syncthreads();

      // ---- MFMA: 2 O-subtiles x 4 S-subtiles per wave (32 O x 64 s) ----
      bf16x8 af[2];
      const __bf16* wbase = wt + (size_t)(kbase + cc) + quad * 8;
#pragma unroll
      for (int ot = 0; ot < 2; ++ot) {
        int o = wv * 32 + ot * 16 + l15;
        af[ot] = *(const bf16x8*)(wbase + (size_t)o * CKTOT);
      }
      bf16x8 bfr[4];
#pragma unroll
      for (int st = 0; st < 4; ++st)
        bfr[st] = *(const bf16x8*)(&colT[st * 16 + l15][quad * 8]);
#pragma unroll
      for (int ot = 0; ot < 2; ++ot)
#pragma unroll
        for (int st = 0; st < 4; ++st)
          acc[ot][st] =
              __builtin_amdgcn_mfma_f32_16x16x32_bf16(af[ot], bfr[st], acc[ot][st], 0, 0, 0);
    }
  }

  // ---- epilogue: atomic accumulate partials into out ----
  float* ob = out + (size_t)(b * Oo) * Ss + s0;
#pragma unroll
  for (int ot = 0; ot < 2; ++ot) {
    int obase = wv * 32 + ot * 16 + quad * 4;
#pragma unroll
    for (int r = 0; r < 4; ++r) {
#pragma unroll
      for (int st = 0; st < 4; ++st) {
        atomicAdd(&ob[(size_t)(obase + r) * Ss + st * 16 + l15], acc[ot][st][r]);
      }
    }
  }
}

extern "C" void kernel_launch(void* const* d_in, const int* in_sizes, int n_in,
                              void* d_out, int out_size, void* d_ws, size_t ws_size,
                              hipStream_t stream) {
  (void)in_sizes; (void)n_in; (void)out_size; (void)ws_size;
  const float* inp = (const float*)d_in[0];
  const float* offset = (const float*)d_in[1];
  const float* mask = (const float*)d_in[2];
  const float* weight = (const float*)d_in[3];
  const float* bias = (const float*)d_in[4];
  float* out = (float*)d_out;

  __bf16* it = (__bf16*)d_ws;                                         // 9,437,184 B
  __bf16* wt = (__bf16*)((char*)d_ws + (size_t)Bb * Ss * Cc * 2);     // 1,179,648 B

  transpose_pack<<<dim3(Ss / 64, Cc / 64, Bb), 256, 0, stream>>>(inp, it);
  weight_pack<<<(Oo * CKTOT) / 256, 256, 0, stream>>>(weight, wt);
  bias_init<<<(Bb * Oo * Ss / 4) / 256, 256, 0, stream>>>(bias, out);
  dcn_main<<<dim3(Ss / STILE, Bb, 3), 512, 0, stream>>>(it, wt, offset, mask, out);
}

// Round 3
// 181.583 us; speedup vs baseline: 1.1608x; 1.0332x over previous
//
#include <hip/hip_runtime.h>
#include <hip/hip_bf16.h>

// DCNv2 forward: B=2, C=256, H=W=96, O=256, K=3x3, stride=1, pad=1, dil=1.
// Pipeline:
//  K1 prep     : (a) input NCHW fp32 -> NHWC bf16, (b) weight -> bf16 [O][k*256+c],
//                (c) out = bias broadcast  (merged; role by blockIdx range)
//  K2 dcn_main : fused bilinear-sample -> LDS col tile -> MFMA, atomicAdd partials
//
// R2 lesson: scattered sample loads were naked on the per-iter critical path
// (MfmaUtil 8%, VALUBusy 13%). Now software-pipelined: double-buffered LDS,
// register prefetch of next chunk's data+weights, ONE lgkm-only barrier/iter
// (s_waitcnt 0xC07F + s_barrier keeps global loads in flight across it).

#define Hh 96
#define Ww 96
#define Cc 256
#define Oo 256
#define Bb 2
#define Kk 9
#define Ss (Hh * Ww)          // 9216
#define CKTOT (Cc * Kk)       // 2304

typedef __bf16 bf16x8 __attribute__((ext_vector_type(8)));
typedef __bf16 bf16x4v __attribute__((ext_vector_type(4)));
typedef __bf16 bf16x2v __attribute__((ext_vector_type(2)));
typedef float f32x4 __attribute__((ext_vector_type(4)));

__device__ __forceinline__ float blo(unsigned u) { return __uint_as_float(u << 16); }
__device__ __forceinline__ float bhi(unsigned u) { return __uint_as_float(u & 0xffff0000u); }

// barrier with LDS drain only — prefetched global loads stay in flight.
// simm16 0xC07F = lgkmcnt(0), expcnt(0), vmcnt(63)=no-wait.
__device__ __forceinline__ void barrier_lgkm() {
  asm volatile("" ::: "memory");
  __builtin_amdgcn_s_waitcnt(0xC07F);
  __builtin_amdgcn_s_barrier();
  asm volatile("" ::: "memory");
}

// ---------------- K1: merged prep ----------------
// blocks [0,1152)        : transpose NCHW fp32 -> NHWC bf16
// blocks [1152,3456)     : weight pack
// blocks [3456,8064)     : bias broadcast into out
__global__ __launch_bounds__(256) void prep(const float* __restrict__ inp,
                                            const float* __restrict__ wsrc,
                                            const float* __restrict__ bias,
                                            __bf16* __restrict__ it,
                                            __bf16* __restrict__ wt,
                                            float* __restrict__ out) {
  __shared__ float tile[64][65];
  const int bx = blockIdx.x;
  const int tid = threadIdx.x;

  if (bx < 1152) {
    const int hw0 = (bx % 144) * 64;
    const int c0 = ((bx / 144) & 3) * 64;
    const int b = bx / 576;
    const int hw_l = tid & 63, cr = tid >> 6;
    const float* src = inp + ((size_t)(b * Cc + c0) * Ss) + hw0;
#pragma unroll
    for (int r = 0; r < 16; ++r) {
      int c_l = r * 4 + cr;
      tile[c_l][hw_l] = src[(size_t)c_l * Ss + hw_l];
    }
    __syncthreads();
    const int cp = (tid & 31) * 2, hr = tid >> 5;
    __bf16* dst = it + ((size_t)(b * Ss + hw0) * Cc) + c0;
#pragma unroll
    for (int r = 0; r < 8; ++r) {
      int hw_s = r * 8 + hr;
      bf16x2v p;
      p.x = (__bf16)tile[cp][hw_s];
      p.y = (__bf16)tile[cp + 1][hw_s];
      *(bf16x2v*)(dst + (size_t)hw_s * Cc + cp) = p;
    }
  } else if (bx < 3456) {
    int i = (bx - 1152) * 256 + tid;  // i < Oo*CKTOT
    int o = i / CKTOT;
    int r = i - o * CKTOT;
    int k = r >> 8, c = r & 255;
    wt[i] = (__bf16)wsrc[(o * Cc + c) * Kk + k];
  } else {
    int i = (bx - 3456) * 256 + tid;  // float4 index, total Bb*Oo*Ss/4
    const int s4 = Ss / 4;
    int o = (i / s4) & (Oo - 1);
    float bv = bias[o];
    ((float4*)out)[i] = make_float4(bv, bv, bv, bv);
  }
}

// ---------------- K2: fused sample + GEMM (pipelined) ----------------
__global__ __launch_bounds__(512, 4) void dcn_main(
    const __bf16* __restrict__ it,     // [B][S][C] bf16
    const __bf16* __restrict__ wt,     // [O][k*256+c] bf16
    const float* __restrict__ offset,  // [B][18][S]
    const float* __restrict__ mask,    // [B][9][S]
    float* __restrict__ out)           // [B][O][S], pre-filled with bias
{
  __shared__ __bf16 colT[2][64][40];  // dbuf [s][c-chunk], rows 80B (16B-aligned)
  __shared__ int4 pa3[3][64];         // per-tap corner offsets
  __shared__ float4 pw3[3][64];       // per-tap corner weights (mask+valid folded)

  const int tid = threadIdx.x;
  const int s0 = blockIdx.x * 64;
  const int b = blockIdx.y;
  const int kg = blockIdx.z;      // taps kg*3 .. kg*3+2
  const int lane = tid & 63;
  const int wv = tid >> 6;        // 8 waves -> O sub-block of 32
  const int quad = lane >> 4;
  const int l15 = lane & 15;
  const int cg = tid & 7;         // c-group (4 ch)
  const int sg = tid >> 3;        // s within tile

  const __bf16* itb = it + (size_t)b * Ss * Cc;

  // ---- params for all 3 taps up front ----
  if (tid < 192) {
    int kk = tid >> 6;            // local tap 0..2
    int sl = tid & 63;
    int k = kg * 3 + kk;
    int s = s0 + sl;
    int ho = s / Ww;
    int wo = s - ho * Ww;
    float dy = offset[((size_t)(b * 18 + 2 * k)) * Ss + s];
    float dx = offset[((size_t)(b * 18 + 2 * k + 1)) * Ss + s];
    float m = mask[((size_t)(b * 9 + k)) * Ss + s];
    float y = (float)(ho - 1 + k / 3) + dy;
    float x = (float)(wo - 1 + k % 3) + dx;
    float fy = floorf(y), fx = floorf(x);
    int y0 = (int)fy, x0 = (int)fx;
    float wy = y - fy, wx = x - fx;
    int y1 = y0 + 1, x1 = x0 + 1;
    float vy0 = (y0 >= 0 && y0 < Hh) ? 1.f : 0.f;
    float vy1 = (y1 >= 0 && y1 < Hh) ? 1.f : 0.f;
    float vx0 = (x0 >= 0 && x0 < Ww) ? 1.f : 0.f;
    float vx1 = (x1 >= 0 && x1 < Ww) ? 1.f : 0.f;
    int y0c = min(max(y0, 0), Hh - 1), y1c = min(max(y1, 0), Hh - 1);
    int x0c = min(max(x0, 0), Ww - 1), x1c = min(max(x1, 0), Ww - 1);
    pa3[kk][sl] = make_int4((y0c * Ww + x0c) * Cc, (y0c * Ww + x1c) * Cc,
                            (y1c * Ww + x0c) * Cc, (y1c * Ww + x1c) * Cc);
    pw3[kk][sl] = make_float4(m * (1.f - wy) * (1.f - wx) * vy0 * vx0,
                              m * (1.f - wy) * wx * vy0 * vx1,
                              m * wy * (1.f - wx) * vy1 * vx0,
                              m * wy * wx * vy1 * vx1);
  }
  __syncthreads();

  f32x4 acc[2][4];
#pragma unroll
  for (int i = 0; i < 2; ++i)
#pragma unroll
    for (int j = 0; j < 4; ++j) acc[i][j] = (f32x4){0.f, 0.f, 0.f, 0.f};

  // ---- pipeline registers (ping-pong) ----
  uint2 D[2][4];     // 4 corner samples (4 ch each)
  float4 PW[2];      // corner weights for this thread's s
  bf16x8 W[2][2];    // weight fragments (2 O-subtiles)

  // chunk index i in [0,24): local tap = i>>3, channel base = (i&7)*32
  auto pf_data = [&](int i, int ph) {
    int kk = i >> 3, cc = (i & 7) << 5;
    int4 a = pa3[kk][sg];
    PW[ph] = pw3[kk][sg];
    const __bf16* bp = itb + (cc + (cg << 2));
    D[ph][0] = *(const uint2*)(bp + a.x);
    D[ph][1] = *(const uint2*)(bp + a.y);
    D[ph][2] = *(const uint2*)(bp + a.z);
    D[ph][3] = *(const uint2*)(bp + a.w);
  };
  auto pf_w = [&](int i, int ph) {
    int k = kg * 3 + (i >> 3), cc = (i & 7) << 5;
    const __bf16* wbase = wt + (size_t)(k * 256 + cc) + quad * 8;
    W[ph][0] = *(const bf16x8*)(wbase + (size_t)(wv * 32 + l15) * CKTOT);
    W[ph][1] = *(const bf16x8*)(wbase + (size_t)(wv * 32 + 16 + l15) * CKTOT);
  };

  auto step = [&](int i, int cur, int nxt) {
    // fill colT[cur] from regs prefetched last iter
    {
      float4 wq = PW[cur];
      uint2 u00 = D[cur][0], u01 = D[cur][1], u10 = D[cur][2], u11 = D[cur][3];
      float r0 = wq.x * blo(u00.x) + wq.y * blo(u01.x) + wq.z * blo(u10.x) + wq.w * blo(u11.x);
      float r1 = wq.x * bhi(u00.x) + wq.y * bhi(u01.x) + wq.z * bhi(u10.x) + wq.w * bhi(u11.x);
      float r2 = wq.x * blo(u00.y) + wq.y * blo(u01.y) + wq.z * blo(u10.y) + wq.w * blo(u11.y);
      float r3 = wq.x * bhi(u00.y) + wq.y * bhi(u01.y) + wq.z * bhi(u10.y) + wq.w * bhi(u11.y);
      bf16x4v rv;
      rv.x = (__bf16)r0;
      rv.y = (__bf16)r1;
      rv.z = (__bf16)r2;
      rv.w = (__bf16)r3;
      *(bf16x4v*)&colT[cur][sg][cg << 2] = rv;
    }
    // issue next chunk's loads (stay in flight across the barrier)
    if (i < 23) {
      pf_data(i + 1, nxt);
      pf_w(i + 1, nxt);
    }
    barrier_lgkm();
    // MFMA on colT[cur] with W[cur]
    bf16x8 bfr[4];
#pragma unroll
    for (int st = 0; st < 4; ++st)
      bfr[st] = *(const bf16x8*)(&colT[cur][st * 16 + l15][quad * 8]);
#pragma unroll
    for (int ot = 0; ot < 2; ++ot)
#pragma unroll
      for (int st = 0; st < 4; ++st)
        acc[ot][st] =
            __builtin_amdgcn_mfma_f32_16x16x32_bf16(W[cur][ot], bfr[st], acc[ot][st], 0, 0, 0);
  };

  pf_data(0, 0);
  pf_w(0, 0);
  for (int ii = 0; ii < 24; ii += 2) {
    step(ii, 0, 1);
    step(ii + 1, 1, 0);
  }

  // ---- epilogue: atomic accumulate partials ----
  float* ob = out + (size_t)(b * Oo) * Ss + s0;
#pragma unroll
  for (int ot = 0; ot < 2; ++ot) {
    int obase = wv * 32 + ot * 16 + quad * 4;
#pragma unroll
    for (int r = 0; r < 4; ++r) {
#pragma unroll
      for (int st = 0; st < 4; ++st) {
        atomicAdd(&ob[(size_t)(obase + r) * Ss + st * 16 + l15], acc[ot][st][r]);
      }
    }
  }
}

extern "C" void kernel_launch(void* const* d_in, const int* in_sizes, int n_in,
                              void* d_out, int out_size, void* d_ws, size_t ws_size,
                              hipStream_t stream) {
  (void)in_sizes; (void)n_in; (void)out_size; (void)ws_size;
  const float* inp = (const float*)d_in[0];
  const float* offset = (const float*)d_in[1];
  const float* mask = (const float*)d_in[2];
  const float* weight = (const float*)d_in[3];
  const float* bias = (const float*)d_in[4];
  float* out = (float*)d_out;

  __bf16* it = (__bf16*)d_ws;                                      // 9,437,184 B
  __bf16* wt = (__bf16*)((char*)d_ws + (size_t)Bb * Ss * Cc * 2);  // 1,179,648 B

  prep<<<8064, 256, 0, stream>>>(inp, weight, bias, it, wt, out);
  dcn_main<<<dim3(Ss / 64, Bb, 3), 512, 0, stream>>>(it, wt, offset, mask, out);
}

// Round 4
// 162.714 us; speedup vs baseline: 1.2954x; 1.1160x over previous
//
#include <hip/hip_runtime.h>
#include <hip/hip_bf16.h>

// DCNv2 forward: B=2, C=256, H=W=96, O=256, K=3x3, stride=1, pad=1, dil=1.
// Pipeline:
//  K1 prep     : (a) input NCHW fp32 -> NHWC bf16, (b) weight -> bf16 [O][k*256+c]
//  K2 dcn_main : fused bilinear-sample -> LDS col tile -> MFMA, direct store+bias
//
// R3 lessons: (a) FETCH_SIZE 71MB vs 9.4MB input -> corner loads were L2 MISSES
//   (both batches thrash 4MB/XCD L2). Fix: XCD swizzle so each XCD owns a
//   contiguous 18-tile s-band (~2.8MB working set incl. weights).
// (b) 14M atomicAdds in epilogue -> removed: full-K blocks, O-split 2 for grid
//   size (576 blocks), direct stores.
// (c) 80B LDS rows gave 3.3M bank conflicts -> back to 96B rows (663K at R2).

#define Hh 96
#define Ww 96
#define Cc 256
#define Oo 256
#define Bb 2
#define Kk 9
#define Ss (Hh * Ww)          // 9216
#define CKTOT (Cc * Kk)       // 2304

typedef __bf16 bf16x8 __attribute__((ext_vector_type(8)));
typedef __bf16 bf16x2v __attribute__((ext_vector_type(2)));
typedef float f32x4 __attribute__((ext_vector_type(4)));

__device__ __forceinline__ float blo(unsigned u) { return __uint_as_float(u << 16); }
__device__ __forceinline__ float bhi(unsigned u) { return __uint_as_float(u & 0xffff0000u); }

// barrier with LDS drain only — prefetched global loads stay in flight.
// simm16 0xC07F = lgkmcnt(0), expcnt(0), vmcnt(63)=no-wait.
__device__ __forceinline__ void barrier_lgkm() {
  asm volatile("" ::: "memory");
  __builtin_amdgcn_s_waitcnt(0xC07F);
  __builtin_amdgcn_s_barrier();
  asm volatile("" ::: "memory");
}

// ---------------- K1: merged prep ----------------
// blocks [0,1152)    : transpose NCHW fp32 -> NHWC bf16
// blocks [1152,3456) : weight pack
__global__ __launch_bounds__(256) void prep(const float* __restrict__ inp,
                                            const float* __restrict__ wsrc,
                                            __bf16* __restrict__ it,
                                            __bf16* __restrict__ wt) {
  __shared__ float tile[64][65];
  const int bx = blockIdx.x;
  const int tid = threadIdx.x;

  if (bx < 1152) {
    const int hw0 = (bx % 144) * 64;
    const int c0 = ((bx / 144) & 3) * 64;
    const int b = bx / 576;
    const int hw_l = tid & 63, cr = tid >> 6;
    const float* src = inp + ((size_t)(b * Cc + c0) * Ss) + hw0;
#pragma unroll
    for (int r = 0; r < 16; ++r) {
      int c_l = r * 4 + cr;
      tile[c_l][hw_l] = src[(size_t)c_l * Ss + hw_l];
    }
    __syncthreads();
    const int cp = (tid & 31) * 2, hr = tid >> 5;
    __bf16* dst = it + ((size_t)(b * Ss + hw0) * Cc) + c0;
#pragma unroll
    for (int r = 0; r < 8; ++r) {
      int hw_s = r * 8 + hr;
      bf16x2v p;
      p.x = (__bf16)tile[cp][hw_s];
      p.y = (__bf16)tile[cp + 1][hw_s];
      *(bf16x2v*)(dst + (size_t)hw_s * Cc + cp) = p;
    }
  } else {
    int i = (bx - 1152) * 256 + tid;  // i < Oo*CKTOT
    int o = i / CKTOT;
    int r = i - o * CKTOT;
    int k = r >> 8, c = r & 255;
    wt[i] = (__bf16)wsrc[(o * Cc + c) * Kk + k];
  }
}

// ---------------- K2: fused sample + GEMM ----------------
// grid (144, 2, 2): x = raw s-tile (swizzled for XCD locality), y = O-half,
// z = batch. 256 thr = 4 waves; each wave: 32 O x 64 s; block: 128 O x 64 s.
__global__ __launch_bounds__(256, 3) void dcn_main(
    const __bf16* __restrict__ it,     // [B][S][C] bf16
    const __bf16* __restrict__ wt,     // [O][k*256+c] bf16
    const float* __restrict__ offset,  // [B][18][S]
    const float* __restrict__ mask,    // [B][9][S]
    const float* __restrict__ bias,    // [O]
    float* __restrict__ out)           // [B][O][S]
{
  __shared__ __bf16 colT[2][64][48];  // dbuf [s][c-chunk], 96B rows (16B-aligned)
  __shared__ int4 pa9[9][64];         // per-tap corner offsets (elements)
  __shared__ float4 pw9[9][64];       // per-tap corner weights (mask+valid folded)

  const int tid = threadIdx.x;
  // XCD swizzle: linear block id % 8 == blockIdx.x % 8 (grid.x=144, 144%8==0).
  // Map so XCD j gets 18 CONTIGUOUS s-tiles -> per-XCD L2 working set ~2.8MB.
  const int tile = (blockIdx.x & 7) * 18 + (blockIdx.x >> 3);
  const int s0 = tile * 64;
  const int bo = blockIdx.y;          // O half: bo*128
  const int b = blockIdx.z;
  const int lane = tid & 63;
  const int wv = tid >> 6;            // 4 waves -> O sub-block of 32
  const int quad = lane >> 4;
  const int l15 = lane & 15;
  const int sg = tid >> 2;            // fill: s within tile (0..63)
  const int cgg = tid & 3;            // fill: 8-ch group (0..3)

  const __bf16* itb = it + (size_t)b * Ss * Cc;

  // ---- bilinear params for all 9 taps up front ----
  for (int idx = tid; idx < 9 * 64; idx += 256) {
    int kk = idx >> 6;
    int sl = idx & 63;
    int s = s0 + sl;
    int ho = s / Ww;
    int wo = s - ho * Ww;
    float dy = offset[((size_t)(b * 18 + 2 * kk)) * Ss + s];
    float dx = offset[((size_t)(b * 18 + 2 * kk + 1)) * Ss + s];
    float m = mask[((size_t)(b * 9 + kk)) * Ss + s];
    float y = (float)(ho - 1 + kk / 3) + dy;
    float x = (float)(wo - 1 + kk % 3) + dx;
    float fy = floorf(y), fx = floorf(x);
    int y0 = (int)fy, x0 = (int)fx;
    float wy = y - fy, wx = x - fx;
    int y1 = y0 + 1, x1 = x0 + 1;
    float vy0 = (y0 >= 0 && y0 < Hh) ? 1.f : 0.f;
    float vy1 = (y1 >= 0 && y1 < Hh) ? 1.f : 0.f;
    float vx0 = (x0 >= 0 && x0 < Ww) ? 1.f : 0.f;
    float vx1 = (x1 >= 0 && x1 < Ww) ? 1.f : 0.f;
    int y0c = min(max(y0, 0), Hh - 1), y1c = min(max(y1, 0), Hh - 1);
    int x0c = min(max(x0, 0), Ww - 1), x1c = min(max(x1, 0), Ww - 1);
    pa9[kk][sl] = make_int4((y0c * Ww + x0c) * Cc, (y0c * Ww + x1c) * Cc,
                            (y1c * Ww + x0c) * Cc, (y1c * Ww + x1c) * Cc);
    pw9[kk][sl] = make_float4(m * (1.f - wy) * (1.f - wx) * vy0 * vx0,
                              m * (1.f - wy) * wx * vy0 * vx1,
                              m * wy * (1.f - wx) * vy1 * vx0,
                              m * wy * wx * vy1 * vx1);
  }
  __syncthreads();

  f32x4 acc[2][4];
#pragma unroll
  for (int i = 0; i < 2; ++i)
#pragma unroll
    for (int j = 0; j < 4; ++j) acc[i][j] = (f32x4){0.f, 0.f, 0.f, 0.f};

  // ---- pipeline registers (ping-pong) ----
  uint4 D[2][4];     // 4 corner samples, 8 ch each (16B)
  float4 PW[2];      // corner weights for this thread's s
  bf16x8 W[2][2];    // weight fragments (2 O-subtiles of this wave's 32 O)

  // chunk i in [0,72): tap = i>>3, channel base cc = (i&7)*32
  auto pf_data = [&](int i, int ph) {
    int kk = i >> 3, cc = (i & 7) << 5;
    int4 a = pa9[kk][sg];
    PW[ph] = pw9[kk][sg];
    const __bf16* bp = itb + (cc + (cgg << 3));
    D[ph][0] = *(const uint4*)(bp + a.x);
    D[ph][1] = *(const uint4*)(bp + a.y);
    D[ph][2] = *(const uint4*)(bp + a.z);
    D[ph][3] = *(const uint4*)(bp + a.w);
  };
  auto pf_w = [&](int i, int ph) {
    int kk = i >> 3, cc = (i & 7) << 5;
    const __bf16* wbase = wt + (size_t)(kk * 256 + cc) + quad * 8;
    int o0 = bo * 128 + wv * 32 + l15;
    W[ph][0] = *(const bf16x8*)(wbase + (size_t)o0 * CKTOT);
    W[ph][1] = *(const bf16x8*)(wbase + (size_t)(o0 + 16) * CKTOT);
  };

  auto step = [&](int i, int cur, int nxt) {
    // fill colT[cur] from regs prefetched last iter (8 channels per thread)
    {
      float4 wq = PW[cur];
      unsigned a00[4] = {D[cur][0].x, D[cur][0].y, D[cur][0].z, D[cur][0].w};
      unsigned a01[4] = {D[cur][1].x, D[cur][1].y, D[cur][1].z, D[cur][1].w};
      unsigned a10[4] = {D[cur][2].x, D[cur][2].y, D[cur][2].z, D[cur][2].w};
      unsigned a11[4] = {D[cur][3].x, D[cur][3].y, D[cur][3].z, D[cur][3].w};
      bf16x8 rv;
#pragma unroll
      for (int w = 0; w < 4; ++w) {
        float rl = wq.x * blo(a00[w]) + wq.y * blo(a01[w]) +
                   wq.z * blo(a10[w]) + wq.w * blo(a11[w]);
        float rh = wq.x * bhi(a00[w]) + wq.y * bhi(a01[w]) +
                   wq.z * bhi(a10[w]) + wq.w * bhi(a11[w]);
        rv[2 * w] = (__bf16)rl;
        rv[2 * w + 1] = (__bf16)rh;
      }
      *(bf16x8*)&colT[cur][sg][cgg << 3] = rv;
    }
    // issue next chunk's loads (stay in flight across the barrier)
    if (i < 71) {
      pf_data(i + 1, nxt);
      pf_w(i + 1, nxt);
    }
    barrier_lgkm();
    // MFMA on colT[cur] with W[cur]
    bf16x8 bfr[4];
#pragma unroll
    for (int st = 0; st < 4; ++st)
      bfr[st] = *(const bf16x8*)(&colT[cur][st * 16 + l15][quad * 8]);
#pragma unroll
    for (int ot = 0; ot < 2; ++ot)
#pragma unroll
      for (int st = 0; st < 4; ++st)
        acc[ot][st] =
            __builtin_amdgcn_mfma_f32_16x16x32_bf16(W[cur][ot], bfr[st], acc[ot][st], 0, 0, 0);
  };

  pf_data(0, 0);
  pf_w(0, 0);
  for (int ii = 0; ii < 72; ii += 2) {
    step(ii, 0, 1);
    step(ii + 1, 1, 0);
  }

  // ---- epilogue: direct store with bias (each (o,s) owned by one thread) ----
#pragma unroll
  for (int ot = 0; ot < 2; ++ot) {
    int o_loc = bo * 128 + wv * 32 + ot * 16 + quad * 4;
#pragma unroll
    for (int r = 0; r < 4; ++r) {
      int o = o_loc + r;
      float bi = bias[o];
      float* op = out + ((size_t)(b * Oo + o)) * Ss + s0 + l15;
#pragma unroll
      for (int st = 0; st < 4; ++st) {
        op[st * 16] = acc[ot][st][r] + bi;
      }
    }
  }
}

extern "C" void kernel_launch(void* const* d_in, const int* in_sizes, int n_in,
                              void* d_out, int out_size, void* d_ws, size_t ws_size,
                              hipStream_t stream) {
  (void)in_sizes; (void)n_in; (void)out_size; (void)ws_size;
  const float* inp = (const float*)d_in[0];
  const float* offset = (const float*)d_in[1];
  const float* mask = (const float*)d_in[2];
  const float* weight = (const float*)d_in[3];
  const float* bias = (const float*)d_in[4];
  float* out = (float*)d_out;

  __bf16* it = (__bf16*)d_ws;                                      // 9,437,184 B
  __bf16* wt = (__bf16*)((char*)d_ws + (size_t)Bb * Ss * Cc * 2);  // 1,179,648 B

  prep<<<3456, 256, 0, stream>>>(inp, weight, it, wt);
  dcn_main<<<dim3(144, 2, Bb), 256, 0, stream>>>(it, wt, offset, mask, bias, out);
}

// Round 5
// 154.742 us; speedup vs baseline: 1.3621x; 1.0515x over previous
//
#include <hip/hip_runtime.h>
#include <hip/hip_bf16.h>

// DCNv2 forward: B=2, C=256, H=W=96, O=256, K=3x3, stride=1, pad=1, dil=1.
// Pipeline:
//  K1 prep     : (a) input NCHW fp32 -> NHWC bf16,
//                (b) weight -> bf16 FRAGMENT-ORDER wtf[kk][cc][osub][lane][8]
//  K2 dcn_main : fused bilinear-sample -> LDS col tile -> MFMA, direct store
//
// R4 lesson: weight A-fragment loads were 64-distinct-line gathers (lane
// stride 4608B) -> 32KB L2 fills per 8KB useful per block-iter; total 2.0GB
// L2 reads at 22 TB/s = the wall. Fragment-order repack makes each wave's
// A-fragment ONE coalesced 1KB load. 512-thr blocks double resident waves
// (grid-limited occupancy) and halve per-thread fill work.

#define Hh 96
#define Ww 96
#define Cc 256
#define Oo 256
#define Bb 2
#define Kk 9
#define Ss (Hh * Ww)          // 9216
#define CKTOT (Cc * Kk)       // 2304

typedef __bf16 bf16x8 __attribute__((ext_vector_type(8)));
typedef __bf16 bf16x4v __attribute__((ext_vector_type(4)));
typedef __bf16 bf16x2v __attribute__((ext_vector_type(2)));
typedef float f32x4 __attribute__((ext_vector_type(4)));
typedef float f32x2 __attribute__((ext_vector_type(2)));

__device__ __forceinline__ f32x2 up2(unsigned u) {
  f32x2 r;
  r.x = __uint_as_float(u << 16);
  r.y = __uint_as_float(u & 0xffff0000u);
  return r;
}

// barrier with LDS drain only — prefetched global loads stay in flight.
// simm16 0xC07F = lgkmcnt(0), expcnt(0), vmcnt(63)=no-wait.
__device__ __forceinline__ void barrier_lgkm() {
  asm volatile("" ::: "memory");
  __builtin_amdgcn_s_waitcnt(0xC07F);
  __builtin_amdgcn_s_barrier();
  asm volatile("" ::: "memory");
}

// ---------------- K1: merged prep ----------------
// blocks [0,1152)    : transpose NCHW fp32 -> NHWC bf16
// blocks [1152,3456) : weight repack to fragment order:
//   wtf[kk][cc][osub][lane][j]: o = osub*16 + (lane&15), ch = cc*32 + (lane>>4)*8 + j
__global__ __launch_bounds__(256) void prep(const float* __restrict__ inp,
                                            const float* __restrict__ wsrc,
                                            __bf16* __restrict__ it,
                                            __bf16* __restrict__ wt) {
  __shared__ float tile[64][65];
  const int bx = blockIdx.x;
  const int tid = threadIdx.x;

  if (bx < 1152) {
    const int hw0 = (bx % 144) * 64;
    const int c0 = ((bx / 144) & 3) * 64;
    const int b = bx / 576;
    const int hw_l = tid & 63, cr = tid >> 6;
    const float* src = inp + ((size_t)(b * Cc + c0) * Ss) + hw0;
#pragma unroll
    for (int r = 0; r < 16; ++r) {
      int c_l = r * 4 + cr;
      tile[c_l][hw_l] = src[(size_t)c_l * Ss + hw_l];
    }
    __syncthreads();
    const int cp = (tid & 31) * 2, hr = tid >> 5;
    __bf16* dst = it + ((size_t)(b * Ss + hw0) * Cc) + c0;
#pragma unroll
    for (int r = 0; r < 8; ++r) {
      int hw_s = r * 8 + hr;
      bf16x2v p;
      p.x = (__bf16)tile[cp][hw_s];
      p.y = (__bf16)tile[cp + 1][hw_s];
      *(bf16x2v*)(dst + (size_t)hw_s * Cc + cp) = p;
    }
  } else {
    int i = (bx - 1152) * 256 + tid;  // i < Oo*CKTOT = 589824
    int j = i & 7;
    int l = (i >> 3) & 63;
    int osub = (i >> 9) & 15;
    int cc = (i >> 13) & 7;
    int kk = i >> 16;
    int o = osub * 16 + (l & 15);
    int ch = cc * 32 + ((l >> 4) << 3) + j;
    wt[i] = (__bf16)wsrc[(o * Cc + ch) * Kk + kk];
  }
}

// ---------------- K2: fused sample + GEMM ----------------
// grid (144, 2, 2): x = s-tile (XCD-swizzled), y = O-half, z = batch.
// 512 thr = 8 waves; each wave: 16 O x 64 s; block: 128 O x 64 s.
__global__ __launch_bounds__(512, 4) void dcn_main(
    const __bf16* __restrict__ it,     // [B][S][C] bf16
    const __bf16* __restrict__ wt,     // fragment-order weights
    const float* __restrict__ offset,  // [B][18][S]
    const float* __restrict__ mask,    // [B][9][S]
    const float* __restrict__ bias,    // [O]
    float* __restrict__ out)           // [B][O][S]
{
  __shared__ __bf16 colT[2][64][48];  // dbuf [s][c-chunk], 96B rows (16B-aligned)
  __shared__ int4 pa9[9][64];         // per-tap corner offsets (elements)
  __shared__ float4 pw9[9][64];       // per-tap corner weights (mask+valid folded)

  const int tid = threadIdx.x;
  // XCD swizzle: XCD j gets 18 contiguous s-tiles -> ~2.8MB L2 working set.
  const int tile = (blockIdx.x & 7) * 18 + (blockIdx.x >> 3);
  const int s0 = tile * 64;
  const int bo = blockIdx.y;          // O half: bo*128
  const int b = blockIdx.z;
  const int lane = tid & 63;
  const int wv = tid >> 6;            // 8 waves -> 16 O each
  const int quad = lane >> 4;
  const int l15 = lane & 15;
  const int sg = tid >> 3;            // fill: s within tile (0..63)
  const int cg = tid & 7;             // fill: 4-ch group (0..7)

  const __bf16* itb = it + (size_t)b * Ss * Cc;

  // ---- bilinear params for all 9 taps up front ----
  for (int idx = tid; idx < 9 * 64; idx += 512) {
    int kk = idx >> 6;
    int sl = idx & 63;
    int s = s0 + sl;
    int ho = s / Ww;
    int wo = s - ho * Ww;
    float dy = offset[((size_t)(b * 18 + 2 * kk)) * Ss + s];
    float dx = offset[((size_t)(b * 18 + 2 * kk + 1)) * Ss + s];
    float m = mask[((size_t)(b * 9 + kk)) * Ss + s];
    float y = (float)(ho - 1 + kk / 3) + dy;
    float x = (float)(wo - 1 + kk % 3) + dx;
    float fy = floorf(y), fx = floorf(x);
    int y0 = (int)fy, x0 = (int)fx;
    float wy = y - fy, wx = x - fx;
    int y1 = y0 + 1, x1 = x0 + 1;
    float vy0 = (y0 >= 0 && y0 < Hh) ? 1.f : 0.f;
    float vy1 = (y1 >= 0 && y1 < Hh) ? 1.f : 0.f;
    float vx0 = (x0 >= 0 && x0 < Ww) ? 1.f : 0.f;
    float vx1 = (x1 >= 0 && x1 < Ww) ? 1.f : 0.f;
    int y0c = min(max(y0, 0), Hh - 1), y1c = min(max(y1, 0), Hh - 1);
    int x0c = min(max(x0, 0), Ww - 1), x1c = min(max(x1, 0), Ww - 1);
    pa9[kk][sl] = make_int4((y0c * Ww + x0c) * Cc, (y0c * Ww + x1c) * Cc,
                            (y1c * Ww + x0c) * Cc, (y1c * Ww + x1c) * Cc);
    pw9[kk][sl] = make_float4(m * (1.f - wy) * (1.f - wx) * vy0 * vx0,
                              m * (1.f - wy) * wx * vy0 * vx1,
                              m * wy * (1.f - wx) * vy1 * vx0,
                              m * wy * wx * vy1 * vx1);
  }
  __syncthreads();

  f32x4 acc[4];
#pragma unroll
  for (int j = 0; j < 4; ++j) acc[j] = (f32x4){0.f, 0.f, 0.f, 0.f};

  // ---- pipeline registers (ping-pong) ----
  uint2 D[2][4];     // 4 corner samples, 4 ch each (8B)
  float4 PW[2];      // corner weights for this thread's s
  bf16x8 W[2];       // A-fragment (this wave's 16-O subtile)

  // chunk i in [0,72): tap = i>>3, c-chunk cc = i&7 (32 ch each)
  auto pf_data = [&](int i, int ph) {
    int kk = i >> 3, ccb = (i & 7) << 5;
    int4 a = pa9[kk][sg];
    PW[ph] = pw9[kk][sg];
    const __bf16* bp = itb + (ccb + (cg << 2));
    D[ph][0] = *(const uint2*)(bp + a.x);
    D[ph][1] = *(const uint2*)(bp + a.y);
    D[ph][2] = *(const uint2*)(bp + a.z);
    D[ph][3] = *(const uint2*)(bp + a.w);
  };
  auto pf_w = [&](int i, int ph) {
    int kk = i >> 3, cc = i & 7;
    int osub = bo * 8 + wv;
    W[ph] = *(const bf16x8*)(wt + (((size_t)((kk * 8 + cc) * 16 + osub)) << 9) + lane * 8);
  };

  auto step = [&](int i, int cur, int nxt) {
    // fill colT[cur] from regs prefetched last iter (4 channels per thread)
    {
      float4 wq = PW[cur];
      f32x2 r01 = up2(D[cur][0].x) * wq.x + up2(D[cur][1].x) * wq.y +
                  up2(D[cur][2].x) * wq.z + up2(D[cur][3].x) * wq.w;
      f32x2 r23 = up2(D[cur][0].y) * wq.x + up2(D[cur][1].y) * wq.y +
                  up2(D[cur][2].y) * wq.z + up2(D[cur][3].y) * wq.w;
      bf16x4v rv;
      rv.x = (__bf16)r01.x;
      rv.y = (__bf16)r01.y;
      rv.z = (__bf16)r23.x;
      rv.w = (__bf16)r23.y;
      *(bf16x4v*)&colT[cur][sg][cg << 2] = rv;
    }
    // issue next chunk's loads (stay in flight across the barrier)
    if (i < 71) {
      pf_data(i + 1, nxt);
      pf_w(i + 1, nxt);
    }
    barrier_lgkm();
    // MFMA on colT[cur] with W[cur]
    bf16x8 bfr[4];
#pragma unroll
    for (int st = 0; st < 4; ++st)
      bfr[st] = *(const bf16x8*)(&colT[cur][st * 16 + l15][quad * 8]);
#pragma unroll
    for (int st = 0; st < 4; ++st)
      acc[st] = __builtin_amdgcn_mfma_f32_16x16x32_bf16(W[cur], bfr[st], acc[st], 0, 0, 0);
  };

  pf_data(0, 0);
  pf_w(0, 0);
  for (int ii = 0; ii < 72; ii += 2) {
    step(ii, 0, 1);
    step(ii + 1, 1, 0);
  }

  // ---- epilogue: direct store with bias (each (o,s) owned by one thread) ----
  int obase = bo * 128 + wv * 16 + quad * 4;
#pragma unroll
  for (int r = 0; r < 4; ++r) {
    int o = obase + r;
    float bi = bias[o];
    float* op = out + ((size_t)(b * Oo + o)) * Ss + s0 + l15;
#pragma unroll
    for (int st = 0; st < 4; ++st) {
      op[st * 16] = acc[st][r] + bi;
    }
  }
}

extern "C" void kernel_launch(void* const* d_in, const int* in_sizes, int n_in,
                              void* d_out, int out_size, void* d_ws, size_t ws_size,
                              hipStream_t stream) {
  (void)in_sizes; (void)n_in; (void)out_size; (void)ws_size;
  const float* inp = (const float*)d_in[0];
  const float* offset = (const float*)d_in[1];
  const float* mask = (const float*)d_in[2];
  const float* weight = (const float*)d_in[3];
  const float* bias = (const float*)d_in[4];
  float* out = (float*)d_out;

  __bf16* it = (__bf16*)d_ws;                                      // 9,437,184 B
  __bf16* wt = (__bf16*)((char*)d_ws + (size_t)Bb * Ss * Cc * 2);  // 1,179,648 B

  prep<<<3456, 256, 0, stream>>>(inp, weight, it, wt);
  dcn_main<<<dim3(144, 2, Bb), 512, 0, stream>>>(it, wt, offset, mask, bias, out);
}

// Round 6
// 128.116 us; speedup vs baseline: 1.6452x; 1.2078x over previous
//
#include <hip/hip_runtime.h>
#include <hip/hip_bf16.h>

// DCNv2 forward: B=2, C=256, H=W=96, O=256, K=3x3, stride=1, pad=1, dil=1.
// Pipeline:
//  K1 prep     : (a) input NCHW fp32 -> NHWC bf16,
//                (b) weight -> bf16 32x32-FRAGMENT order wt[kk][cc16][osub][lane][8]
//  K2 dcn_main : per tap: burst-fill 32s x 256ch tap tile into LDS (1 barrier),
//                then 16 chunks of mfma_32x32x16 with register-prefetched weights.
//
// R5 lesson: 72 barrier-coupled steps serialized everything (all pipes <35%);
// per-chunk machinery (param LDS reads, ping-pong, drains) cost ~108 VALU
// inst/thread/step. Now 9 barriers total, fill is one 16-load burst, compute
// is barrier-free with 1-chunk register lookahead. XOR-swizzled LDS (g^=s&7,
// stride 512B) -> ~2-way max conflicts on both write and read.

#define Hh 96
#define Ww 96
#define Cc 256
#define Oo 256
#define Bb 2
#define Kk 9
#define Ss (Hh * Ww)          // 9216
#define CKTOT (Cc * Kk)       // 2304

typedef __bf16 bf16x8 __attribute__((ext_vector_type(8)));
typedef __bf16 bf16x2v __attribute__((ext_vector_type(2)));
typedef float f32x16 __attribute__((ext_vector_type(16)));
typedef float f32x2 __attribute__((ext_vector_type(2)));

__device__ __forceinline__ f32x2 up2(unsigned u) {
  f32x2 r;
  r.x = __uint_as_float(u << 16);
  r.y = __uint_as_float(u & 0xffff0000u);
  return r;
}

// barrier with LDS drain only — prefetched global loads stay in flight.
// simm16 0xC07F = lgkmcnt(0), expcnt(0), vmcnt(63)=no-wait.
__device__ __forceinline__ void barrier_lgkm() {
  asm volatile("" ::: "memory");
  __builtin_amdgcn_s_waitcnt(0xC07F);
  __builtin_amdgcn_s_barrier();
  asm volatile("" ::: "memory");
}

// ---------------- K1: merged prep ----------------
// blocks [0,1152)    : transpose NCHW fp32 -> NHWC bf16
// blocks [1152,3456) : weight repack to 32x32 A-fragment order:
//   wt[kk][cc][osub][lane][j]: o = osub*32 + (lane&31), ch = cc*16 + (lane>>5)*8 + j
__global__ __launch_bounds__(256) void prep(const float* __restrict__ inp,
                                            const float* __restrict__ wsrc,
                                            __bf16* __restrict__ it,
                                            __bf16* __restrict__ wt) {
  __shared__ float tile[64][65];
  const int bx = blockIdx.x;
  const int tid = threadIdx.x;

  if (bx < 1152) {
    const int hw0 = (bx % 144) * 64;
    const int c0 = ((bx / 144) & 3) * 64;
    const int b = bx / 576;
    const int hw_l = tid & 63, cr = tid >> 6;
    const float* src = inp + ((size_t)(b * Cc + c0) * Ss) + hw0;
#pragma unroll
    for (int r = 0; r < 16; ++r) {
      int c_l = r * 4 + cr;
      tile[c_l][hw_l] = src[(size_t)c_l * Ss + hw_l];
    }
    __syncthreads();
    const int cp = (tid & 31) * 2, hr = tid >> 5;
    __bf16* dst = it + ((size_t)(b * Ss + hw0) * Cc) + c0;
#pragma unroll
    for (int r = 0; r < 8; ++r) {
      int hw_s = r * 8 + hr;
      bf16x2v p;
      p.x = (__bf16)tile[cp][hw_s];
      p.y = (__bf16)tile[cp + 1][hw_s];
      *(bf16x2v*)(dst + (size_t)hw_s * Cc + cp) = p;
    }
  } else {
    int i = (bx - 1152) * 256 + tid;  // i < Oo*CKTOT = 589824
    int j = i & 7;
    int l = (i >> 3) & 63;
    int osub = (i >> 9) & 7;
    int cc = (i >> 12) & 15;
    int kk = i >> 16;
    int o = osub * 32 + (l & 31);
    int ch = cc * 16 + ((l >> 5) << 3) + j;
    wt[i] = (__bf16)wsrc[(o * Cc + ch) * Kk + kk];
  }
}

// ---------------- K2: fused sample + GEMM ----------------
// grid (288, 2): x = 32-s tile (XCD-swizzled), y = batch.
// 256 thr = 4 waves; wave wv covers o in [wv*64, wv*64+64); block = 32s x 256 O.
__global__ __launch_bounds__(256, 3) void dcn_main(
    const __bf16* __restrict__ it,     // [B][S][C] bf16
    const __bf16* __restrict__ wt,     // 32x32-fragment-order weights
    const float* __restrict__ offset,  // [B][18][S]
    const float* __restrict__ mask,    // [B][9][S]
    const float* __restrict__ bias,    // [O]
    float* __restrict__ out)           // [B][O][S]
{
  __shared__ __bf16 colT[2][32 * 256];  // dbuf tap tile, XOR-swizzled granules
  __shared__ int4 pa9[9][32];           // per-tap corner offsets (elements)
  __shared__ float4 pw9[9][32];         // per-tap corner weights (mask+valid folded)

  const int tid = threadIdx.x;
  // XCD swizzle: XCD j gets 36 contiguous 32-s tiles (~2.6MB L2 working set).
  const int tile = (blockIdx.x & 7) * 36 + (blockIdx.x >> 3);
  const int s0 = tile * 32;
  const int b = blockIdx.y;
  const int lane = tid & 63;
  const int wv = tid >> 6;            // 4 waves -> 64 O each
  const int sB = lane & 31;           // B-frag / C-frag spatial lane
  const int hi = lane >> 5;
  const int fs = tid >> 3;            // fill: s-row 0..31
  const int fg = tid & 7;             // fill: granule group 0..7

  const __bf16* itb = it + (size_t)b * Ss * Cc;

  // ---- bilinear params for all 9 taps up front ----
  for (int idx = tid; idx < 9 * 32; idx += 256) {
    int kk = idx >> 5;
    int sl = idx & 31;
    int s = s0 + sl;
    int ho = s / Ww;
    int wo = s - ho * Ww;
    float dy = offset[((size_t)(b * 18 + 2 * kk)) * Ss + s];
    float dx = offset[((size_t)(b * 18 + 2 * kk + 1)) * Ss + s];
    float m = mask[((size_t)(b * 9 + kk)) * Ss + s];
    float y = (float)(ho - 1 + kk / 3) + dy;
    float x = (float)(wo - 1 + kk % 3) + dx;
    float fy = floorf(y), fx = floorf(x);
    int y0 = (int)fy, x0 = (int)fx;
    float wy = y - fy, wx = x - fx;
    int y1 = y0 + 1, x1 = x0 + 1;
    float vy0 = (y0 >= 0 && y0 < Hh) ? 1.f : 0.f;
    float vy1 = (y1 >= 0 && y1 < Hh) ? 1.f : 0.f;
    float vx0 = (x0 >= 0 && x0 < Ww) ? 1.f : 0.f;
    float vx1 = (x1 >= 0 && x1 < Ww) ? 1.f : 0.f;
    int y0c = min(max(y0, 0), Hh - 1), y1c = min(max(y1, 0), Hh - 1);
    int x0c = min(max(x0, 0), Ww - 1), x1c = min(max(x1, 0), Ww - 1);
    pa9[kk][sl] = make_int4((y0c * Ww + x0c) * Cc, (y0c * Ww + x1c) * Cc,
                            (y1c * Ww + x0c) * Cc, (y1c * Ww + x1c) * Cc);
    pw9[kk][sl] = make_float4(m * (1.f - wy) * (1.f - wx) * vy0 * vx0,
                              m * (1.f - wy) * wx * vy0 * vx1,
                              m * wy * (1.f - wx) * vy1 * vx0,
                              m * wy * wx * vy1 * vx1);
  }
  __syncthreads();

  f32x16 acc0, acc1;
#pragma unroll
  for (int j = 0; j < 16; ++j) { acc0[j] = 0.f; acc1[j] = 0.f; }

  // weight A-fragment load: wt[((kk*16+cc)*8 + osub)*512 + lane*8]
  auto ldW = [&](int kk, int cc, int which) {
    size_t idx = (size_t)((kk * 16 + cc) * 8 + wv * 2 + which);
    return *(const bf16x8*)(wt + (idx << 9) + (lane << 3));
  };
  // B fragment from LDS: row sB, logical granule 2cc+hi, XOR-swizzled
  auto ldB = [&](int buf, int cc) {
    int g = ((2 * cc + hi) ^ (sB & 7)) << 3;
    return *(const bf16x8*)(&colT[buf][sB * 256 + g]);
  };

  for (int kk = 0; kk < Kk; ++kk) {
    const int buf = kk & 1;
    // ---- fill: 16 burst dwordx4 corner loads, bilinear, swizzled LDS write ----
    {
      int4 a = pa9[kk][fs];
      float4 wq = pw9[kk][fs];
      __bf16* drow = &colT[buf][fs * 256];
#pragma unroll
      for (int it2 = 0; it2 < 4; ++it2) {
        int g = fg + it2 * 8;           // logical granule (8 ch)
        const __bf16* p = itb + g * 8;
        uint4 c00 = *(const uint4*)(p + a.x);
        uint4 c01 = *(const uint4*)(p + a.y);
        uint4 c10 = *(const uint4*)(p + a.z);
        uint4 c11 = *(const uint4*)(p + a.w);
        unsigned u0[4] = {c00.x, c00.y, c00.z, c00.w};
        unsigned u1[4] = {c01.x, c01.y, c01.z, c01.w};
        unsigned u2[4] = {c10.x, c10.y, c10.z, c10.w};
        unsigned u3[4] = {c11.x, c11.y, c11.z, c11.w};
        bf16x8 rv;
#pragma unroll
        for (int w = 0; w < 4; ++w) {
          f32x2 r = up2(u0[w]) * wq.x + up2(u1[w]) * wq.y +
                    up2(u2[w]) * wq.z + up2(u3[w]) * wq.w;
          rv[2 * w] = (__bf16)r.x;
          rv[2 * w + 1] = (__bf16)r.y;
        }
        *(bf16x8*)(drow + ((g ^ (fs & 7)) << 3)) = rv;
      }
    }
    // chunk-0 weights issued pre-barrier; lgkm-only barrier keeps them in flight
    bf16x8 Wacur = ldW(kk, 0, 0);
    bf16x8 Wbcur = ldW(kk, 0, 1);
    barrier_lgkm();

    // ---- compute: 16 chunks, register lookahead, no barriers ----
    bf16x8 Bcur = ldB(buf, 0);
#pragma unroll
    for (int cc = 0; cc < 16; ++cc) {
      bf16x8 Bn, Wan, Wbn;
      if (cc < 15) {
        Bn = ldB(buf, cc + 1);
        Wan = ldW(kk, cc + 1, 0);
        Wbn = ldW(kk, cc + 1, 1);
      }
      acc0 = __builtin_amdgcn_mfma_f32_32x32x16_bf16(Wacur, Bcur, acc0, 0, 0, 0);
      acc1 = __builtin_amdgcn_mfma_f32_32x32x16_bf16(Wbcur, Bcur, acc1, 0, 0, 0);
      if (cc < 15) {
        Bcur = Bn;
        Wacur = Wan;
        Wbcur = Wbn;
      }
    }
  }

  // ---- epilogue: direct store with bias ----
  // D mapping (32x32): col(s)=lane&31, row(o-off)=(r&3)+8*(r>>2)+4*(lane>>5)
  float* ob = out + (size_t)b * Oo * Ss + s0 + sB;
#pragma unroll
  for (int os = 0; os < 2; ++os) {
#pragma unroll
    for (int r = 0; r < 16; ++r) {
      int o = wv * 64 + os * 32 + (r & 3) + 8 * (r >> 2) + 4 * hi;
      float v = (os ? acc1[r] : acc0[r]) + bias[o];
      ob[(size_t)o * Ss] = v;
    }
  }
}

extern "C" void kernel_launch(void* const* d_in, const int* in_sizes, int n_in,
                              void* d_out, int out_size, void* d_ws, size_t ws_size,
                              hipStream_t stream) {
  (void)in_sizes; (void)n_in; (void)out_size; (void)ws_size;
  const float* inp = (const float*)d_in[0];
  const float* offset = (const float*)d_in[1];
  const float* mask = (const float*)d_in[2];
  const float* weight = (const float*)d_in[3];
  const float* bias = (const float*)d_in[4];
  float* out = (float*)d_out;

  __bf16* it = (__bf16*)d_ws;                                      // 9,437,184 B
  __bf16* wt = (__bf16*)((char*)d_ws + (size_t)Bb * Ss * Cc * 2);  // 1,179,648 B

  prep<<<3456, 256, 0, stream>>>(inp, weight, it, wt);
  dcn_main<<<dim3(288, Bb), 256, 0, stream>>>(it, wt, offset, mask, bias, out);
}